// Round 6
// baseline (161.325 us; speedup 1.0000x reference)
//
#include <hip/hip_runtime.h>
#include <math.h>

#define NB 32     // batch
#define NC 256    // channels
#define NT 512    // time
#define NH 8      // heads
#define ND 32     // head dim
#define SCALE 0.17677669529663687f            // 1/sqrt(32)
#define LOG2E 1.4426950408889634f
#define QSCALE (SCALE * LOG2E)                // folded into Q at qkv epilogue
#define MASKVAL (-1.4426950408889634e9f)      // -1e9 * log2e (base-2 domain)
#define DEFER_THR 8.0f                        // defer-max threshold (base-2)

typedef __attribute__((ext_vector_type(8))) __bf16 bf16x8;
typedef __attribute__((ext_vector_type(4))) __bf16 bf16x4;
typedef __attribute__((ext_vector_type(4))) float  f32x4;

static __device__ __forceinline__ f32x4 mfma16x16x32(bf16x8 a, bf16x8 b, f32x4 c) {
    return __builtin_amdgcn_mfma_f32_16x16x32_bf16(a, b, c, 0, 0, 0);
}

// =====================================================================
// Kernel 1: fused QKV projection via bf16 MFMA (unchanged from round 4).
// Q pre-scaled by 1/sqrt(d)*log2(e) for base-2 softmax downstream.
// =====================================================================
__global__ __launch_bounds__(256) void qkv_mfma(
    const float* __restrict__ seq,
    const float* __restrict__ Wq, const float* __restrict__ bq,
    const float* __restrict__ Wk, const float* __restrict__ bk,
    const float* __restrict__ Wv, const float* __restrict__ bv,
    __bf16* __restrict__ Qh, __bf16* __restrict__ Kh, __bf16* __restrict__ Vh,
    float* __restrict__ stats)
{
    __shared__ __bf16 As[64][264];      // [t][c]
    __shared__ __bf16 Ws[3][64][40];    // [p][co][c-chunk]

    const int tid = threadIdx.x;
    const int t0  = blockIdx.x * 64;
    const int co0 = blockIdx.y * 64;
    const int bb  = blockIdx.z;

    if (blockIdx.x == 0 && blockIdx.y == 0 && bb == 0 && tid < 128)
        ((float4*)stats)[tid] = make_float4(0.f, 0.f, 0.f, 0.f);

    {
        const int cl = tid & 15;
        const int t4 = (tid >> 4) * 4;
        for (int it = 0; it < 16; ++it) {
            const int c = it*16 + cl;
            const float4 v = *(const float4*)&seq[((size_t)(bb*NC + c))*NT + t0 + t4];
            As[t4+0][c] = (__bf16)v.x;
            As[t4+1][c] = (__bf16)v.y;
            As[t4+2][c] = (__bf16)v.z;
            As[t4+3][c] = (__bf16)v.w;
        }
    }

    const float* Wp[3] = {Wq, Wk, Wv};

    f32x4 acc[3][4];
    #pragma unroll
    for (int p = 0; p < 3; ++p)
        #pragma unroll
        for (int n = 0; n < 4; ++n) acc[p][n] = (f32x4)0.f;

    const int l   = tid & 63;
    const int w   = tid >> 6;
    const int lr  = l & 15;
    const int lk8 = (l >> 4) * 8;

    int wp_[6], wco[6], wc4[6];
    #pragma unroll
    for (int i = 0; i < 6; ++i) {
        const int lin = i*256 + tid;
        wp_[i] = lin >> 9;
        const int r = lin & 511;
        wco[i] = r >> 3;
        wc4[i] = (r & 7) * 4;
    }

    float4 wreg[6];
    #pragma unroll
    for (int i = 0; i < 6; ++i)
        wreg[i] = *(const float4*)&Wp[wp_[i]][(size_t)(co0 + wco[i])*NC + wc4[i]];

    for (int kc = 0; kc < 8; ++kc) {
        __syncthreads();
        #pragma unroll
        for (int i = 0; i < 6; ++i) {
            bf16x4 wb;
            wb[0] = (__bf16)wreg[i].x; wb[1] = (__bf16)wreg[i].y;
            wb[2] = (__bf16)wreg[i].z; wb[3] = (__bf16)wreg[i].w;
            *(bf16x4*)&Ws[wp_[i]][wco[i]][wc4[i]] = wb;
        }
        __syncthreads();

        if (kc < 7) {
            #pragma unroll
            for (int i = 0; i < 6; ++i)
                wreg[i] = *(const float4*)&Wp[wp_[i]][(size_t)(co0 + wco[i])*NC + (kc+1)*32 + wc4[i]];
        }

        const bf16x8 a = *(const bf16x8*)&As[w*16 + lr][kc*32 + lk8];
        #pragma unroll
        for (int p = 0; p < 3; ++p)
            #pragma unroll
            for (int n = 0; n < 4; ++n) {
                const bf16x8 bfr = *(const bf16x8*)&Ws[p][n*16 + lr][lk8];
                acc[p][n] = mfma16x16x32(a, bfr, acc[p][n]);
            }
    }

    const float* bias[3] = {bq, bk, bv};
    __bf16* outp[3] = {Qh, Kh, Vh};
    #pragma unroll
    for (int p = 0; p < 3; ++p) {
        #pragma unroll
        for (int n = 0; n < 4; ++n) {
            const int c  = co0 + n*16 + lr;
            const int hh = c >> 5, jj = c & 31;
            const float bv_ = bias[p][c];
            const float sc  = (p == 0) ? QSCALE : 1.f;
            __bf16* op = outp[p] + ((size_t)(bb*NH + hh)*NT)*ND + jj;
            #pragma unroll
            for (int r = 0; r < 4; ++r) {
                const int t = t0 + w*16 + (l>>4)*4 + r;
                op[(size_t)t*ND] = (__bf16)(fmaxf(acc[p][n][r] + bv_, 0.f) * sc);
            }
        }
    }
}

// =====================================================================
// Kernel 2: flash attention. 512 threads = 8 waves; wave w owns q-rows
// [w*16, w*16+16) of a 128-row tile. s-chunks of 64.
//  - K A-fragments direct from global (L1-broadcast), register prefetch
//  - V^T and P in LDS with 128B rows + XOR swizzle (col ^= (row&7)<<3)
//  - in-register softmax (swapped mfma), ballot key-mask, defer-max
//  - 2 barriers/chunk (VTs staging only); PA is wave-private
// Writes pre-BN x to out[b,c,t]; fused BN partial stats via atomics.
// =====================================================================
__global__ __launch_bounds__(512) void attn_mfma(
    const __bf16* __restrict__ Qh, const __bf16* __restrict__ Kh,
    const __bf16* __restrict__ Vh, const int* __restrict__ mask,
    float* __restrict__ xout, float* __restrict__ stats)
{
    __shared__ __bf16 VTs[32*64];     // [j][s] 128B rows, swizzled
    __shared__ __bf16 PA[128*64];     // [t][s] 128B rows, swizzled, wave-private rows
    __shared__ float  bnsum[32][8];
    __shared__ float  bnsum2[32][8];

    const int tid = threadIdx.x;
    const int t0  = blockIdx.x * 128;
    const int h   = blockIdx.y;
    const int bb  = blockIdx.z;
    const int bh  = bb*NH + h;
    const __bf16* Qp = Qh + (size_t)bh*NT*ND;
    const __bf16* Kp = Kh + (size_t)bh*NT*ND;
    const __bf16* Vp = Vh + (size_t)bh*NT*ND;

    const int l   = tid & 63;
    const int w   = tid >> 6;       // wave 0..7
    const int lr  = l & 15;
    const int g   = l >> 4;         // 0..3
    const int swz = (lr & 7) << 3;  // element-level XOR key for 128B rows

    // Q B-fragment: constant all kernel.
    const bf16x8 qb = *(const bf16x8*)&Qp[(size_t)(t0 + w*16 + lr)*ND + g*8];

    f32x4 accO[2];                  // [jt]: O^T[j=jt*16+g*4+r][t=w*16+lr]
    accO[0] = (f32x4)0.f; accO[1] = (f32x4)0.f;
    float m_run = -1e30f, l_run = 0.f;

    // V staging map: thread -> (s, j4); 512 thr x ushort4 = 4KB chunk
    const int v_s = tid >> 3, v_j4 = (tid & 7) * 4;

    // preload chunk 0: V regs, K A-frags, mask ballot
    ushort4 vreg = *(const ushort4*)&Vp[(size_t)v_s*ND + v_j4];
    bf16x8 kA[4];
    #pragma unroll
    for (int st = 0; st < 4; ++st)
        kA[st] = *(const bf16x8*)&Kp[(size_t)(st*16 + lr)*ND + g*8];
    unsigned long long mw = __ballot(mask[bb*NT + l] != 0);

    for (int s0 = 0; s0 < NT; s0 += 64) {
        __syncthreads();   // prior chunk's PV done reading VTs
        {   // stage V^T (transposing scatter, swizzled)
            const __bf16* vb = (const __bf16*)&vreg;
            #pragma unroll
            for (int kk = 0; kk < 4; ++kk) {
                const int j = v_j4 + kk;
                VTs[j*64 + (v_s ^ ((j & 7) << 3))] = vb[kk];
            }
        }
        __syncthreads();   // VTs ready

        // capture current-chunk operands, then prefetch next chunk
        const unsigned long long mwc = mw;
        bf16x8 kAc[4];
        #pragma unroll
        for (int st = 0; st < 4; ++st) kAc[st] = kA[st];
        if (s0 + 64 < NT) {
            const int sn = s0 + 64;
            vreg = *(const ushort4*)&Vp[(size_t)(sn + v_s)*ND + v_j4];
            #pragma unroll
            for (int st = 0; st < 4; ++st)
                kA[st] = *(const bf16x8*)&Kp[(size_t)(sn + st*16 + lr)*ND + g*8];
            mw = __ballot(mask[bb*NT + sn + l] != 0);
        }

        // ---- S^T tiles: lane holds s = st*16 + g*4 + r for q-row t=w*16+lr
        f32x4 sst[4];
        #pragma unroll
        for (int st = 0; st < 4; ++st)
            sst[st] = mfma16x16x32(kAc[st], qb, (f32x4)0.f);

        // ---- key mask + row max (in-register + 2 shfl) ----
        float v[16];
        float mx = -1e30f;
        #pragma unroll
        for (int st = 0; st < 4; ++st)
            #pragma unroll
            for (int r = 0; r < 4; ++r) {
                const int s = st*16 + g*4 + r;
                const float val = ((mwc >> s) & 1ull) ? sst[st][r] : MASKVAL;
                v[st*4+r] = val;
                mx = fmaxf(mx, val);
            }
        mx = fmaxf(mx, __shfl_xor(mx, 16));
        mx = fmaxf(mx, __shfl_xor(mx, 32));

        // ---- defer-max: only rescale when the max actually grew ----
        if (!__all(mx <= m_run + DEFER_THR)) {
            const float m_new = fmaxf(m_run, mx);
            const float f = exp2f(m_run - m_new);
            l_run *= f;
            #pragma unroll
            for (int jt = 0; jt < 2; ++jt)
                #pragma unroll
                for (int r = 0; r < 4; ++r) accO[jt][r] *= f;
            m_run = m_new;
        }

        // ---- exp2, partial sum, P -> bf16 PA (wave-private, swizzled) ----
        float ssum = 0.f;
        #pragma unroll
        for (int st = 0; st < 4; ++st) {
            bf16x4 pb4;
            #pragma unroll
            for (int r = 0; r < 4; ++r) {
                const float p = exp2f(v[st*4+r] - m_run);
                ssum += p;
                pb4[r] = (__bf16)p;
            }
            *(bf16x4*)&PA[(w*16 + lr)*64 + ((st*16 + g*4) ^ swz)] = pb4;
        }
        ssum += __shfl_xor(ssum, 16);
        ssum += __shfl_xor(ssum, 32);
        l_run += ssum;

        // ---- PV: O^T += V^T @ P^T (same-wave PA rows; lgkmcnt orders) ----
        #pragma unroll
        for (int kh = 0; kh < 2; ++kh) {
            const bf16x8 pb = *(const bf16x8*)&PA[(w*16 + lr)*64 + ((kh*32 + g*8) ^ swz)];
            #pragma unroll
            for (int jt = 0; jt < 2; ++jt) {
                const bf16x8 va = *(const bf16x8*)&VTs[(jt*16 + lr)*64 + ((kh*32 + g*8) ^ swz)];
                accO[jt] = mfma16x16x32(va, pb, accO[jt]);
            }
        }
    }

    // ---- epilogue: 1/l * qmask, store x[b,c,t] (O^T layout); BN partials ----
    const int t = t0 + w*16 + lr;
    const float rl = mask[bb*NT + t] ? (1.f / l_run) : 0.f;
    float psum[2][4], psq[2][4];
    #pragma unroll
    for (int jt = 0; jt < 2; ++jt) {
        #pragma unroll
        for (int r = 0; r < 4; ++r) {
            const int c = h*ND + jt*16 + g*4 + r;
            const float o = accO[jt][r] * rl;
            xout[((size_t)(bb*NC + c))*NT + t] = o;
            psum[jt][r] = o;
            psq[jt][r]  = o*o;
        }
    }
    #pragma unroll
    for (int jt = 0; jt < 2; ++jt)
        #pragma unroll
        for (int r = 0; r < 4; ++r)
            #pragma unroll
            for (int off = 1; off < 16; off <<= 1) {
                psum[jt][r] += __shfl_xor(psum[jt][r], off);
                psq[jt][r]  += __shfl_xor(psq[jt][r],  off);
            }
    if (lr == 0) {
        #pragma unroll
        for (int jt = 0; jt < 2; ++jt)
            #pragma unroll
            for (int r = 0; r < 4; ++r) {
                bnsum [jt*16 + g*4 + r][w] = psum[jt][r];
                bnsum2[jt*16 + g*4 + r][w] = psq[jt][r];
            }
    }
    __syncthreads();
    if (tid < 32) {
        float s = 0.f, s2 = 0.f;
        #pragma unroll
        for (int ww = 0; ww < 8; ++ww) { s += bnsum[tid][ww]; s2 += bnsum2[tid][ww]; }
        atomicAdd(&stats[h*ND + tid], s);
        atomicAdd(&stats[NC + h*ND + tid], s2);
    }
}

// =====================================================================
// Kernel 3: BN normalize + affine + re-mask, in place on d_out.
// =====================================================================
__global__ __launch_bounds__(256) void bn_apply_kernel(
    float* __restrict__ x, const float* __restrict__ stats,
    const float* __restrict__ gamma, const float* __restrict__ beta,
    const int* __restrict__ mask)
{
    const int idx = blockIdx.x*256 + threadIdx.x;
    const int t4 = idx & 127;
    const int c  = (idx >> 7) & 255;
    const int bb = idx >> 15;
    float4 v = ((const float4*)x)[idx];
    const int4 mk = *(const int4*)&mask[bb*NT + t4*4];
    const float mean = stats[c] * (1.f/16384.f);
    const float var  = fmaxf(stats[NC + c]*(1.f/16384.f) - mean*mean, 0.f);
    const float rstd = rsqrtf(var + 1e-5f);
    const float g = gamma[c], be = beta[c];
    v.x = mk.x ? fmaf((v.x - mean)*rstd, g, be) : 0.f;
    v.y = mk.y ? fmaf((v.y - mean)*rstd, g, be) : 0.f;
    v.z = mk.z ? fmaf((v.z - mean)*rstd, g, be) : 0.f;
    v.w = mk.w ? fmaf((v.w - mean)*rstd, g, be) : 0.f;
    ((float4*)x)[idx] = v;
}

extern "C" void kernel_launch(void* const* d_in, const int* in_sizes, int n_in,
                              void* d_out, int out_size, void* d_ws, size_t ws_size,
                              hipStream_t stream)
{
    const float* seq   = (const float*)d_in[0];
    const int*   mask  = (const int*)  d_in[1];
    const float* Wq    = (const float*)d_in[2];
    const float* bq    = (const float*)d_in[3];
    const float* Wk    = (const float*)d_in[4];
    const float* bk    = (const float*)d_in[5];
    const float* Wv    = (const float*)d_in[6];
    const float* bv    = (const float*)d_in[7];
    const float* gamma = (const float*)d_in[8];
    const float* beta  = (const float*)d_in[9];
    float* out = (float*)d_out;

    const size_t perMat = (size_t)NB*NH*NT*ND;
    __bf16* Qh = (__bf16*)d_ws;
    __bf16* Kh = Qh + perMat;
    __bf16* Vh = Kh + perMat;
    float* stats = (float*)(Vh + perMat);

    qkv_mfma<<<dim3(NT/64, NC/64, NB), 256, 0, stream>>>(
        seq, Wq, bq, Wk, bk, Wv, bv, Qh, Kh, Vh, stats);
    attn_mfma<<<dim3(NT/128, NH, NB), 512, 0, stream>>>(
        Qh, Kh, Vh, mask, out, stats);
    bn_apply_kernel<<<dim3((NB*NC*NT/4)/256), 256, 0, stream>>>(
        out, stats, gamma, beta, mask);
}

// Round 7
// 147.483 us; speedup vs baseline: 1.0939x; 1.0939x over previous
//
#include <hip/hip_runtime.h>
#include <math.h>

#define NB 32     // batch
#define NC 256    // channels
#define NT 512    // time
#define NH 8      // heads
#define ND 32     // head dim
#define SCALE 0.17677669529663687f            // 1/sqrt(32)
#define LOG2E 1.4426950408889634f
#define QSCALE (SCALE * LOG2E)                // folded into Q at qkv epilogue
#define DEFER_THR 8.0f                        // defer-max threshold (base-2)

typedef __attribute__((ext_vector_type(8))) __bf16 bf16x8;
typedef __attribute__((ext_vector_type(4))) __bf16 bf16x4;
typedef __attribute__((ext_vector_type(4))) float  f32x4;

static __device__ __forceinline__ f32x4 mfma16x16x32(bf16x8 a, bf16x8 b, f32x4 c) {
    return __builtin_amdgcn_mfma_f32_16x16x32_bf16(a, b, c, 0, 0, 0);
}

// =====================================================================
// Kernel 1: fused QKV projection via bf16 MFMA.
// Q pre-scaled by 1/sqrt(d)*log2(e). Q,K out in [b,h,t,j] (natural).
// V out TRANSPOSED [b,h,j,t] with masked key rows zeroed (mask-as-data:
// downstream PV needs no P masking; l comes from a mask column).
// =====================================================================
__global__ __launch_bounds__(256) void qkv_mfma(
    const float* __restrict__ seq, const int* __restrict__ mask,
    const float* __restrict__ Wq, const float* __restrict__ bq,
    const float* __restrict__ Wk, const float* __restrict__ bk,
    const float* __restrict__ Wv, const float* __restrict__ bv,
    __bf16* __restrict__ Qh, __bf16* __restrict__ Kh, __bf16* __restrict__ VhT,
    float* __restrict__ stats)
{
    __shared__ __bf16 As[64][264];      // [t][c]
    __shared__ __bf16 Ws[3][64][40];    // [p][co][c-chunk]

    const int tid = threadIdx.x;
    const int t0  = blockIdx.x * 64;
    const int co0 = blockIdx.y * 64;
    const int bb  = blockIdx.z;

    if (blockIdx.x == 0 && blockIdx.y == 0 && bb == 0 && tid < 128)
        ((float4*)stats)[tid] = make_float4(0.f, 0.f, 0.f, 0.f);

    {
        const int cl = tid & 15;
        const int t4 = (tid >> 4) * 4;
        for (int it = 0; it < 16; ++it) {
            const int c = it*16 + cl;
            const float4 v = *(const float4*)&seq[((size_t)(bb*NC + c))*NT + t0 + t4];
            As[t4+0][c] = (__bf16)v.x;
            As[t4+1][c] = (__bf16)v.y;
            As[t4+2][c] = (__bf16)v.z;
            As[t4+3][c] = (__bf16)v.w;
        }
    }

    const float* Wp[3] = {Wq, Wk, Wv};

    f32x4 acc[3][4];
    #pragma unroll
    for (int p = 0; p < 3; ++p)
        #pragma unroll
        for (int n = 0; n < 4; ++n) acc[p][n] = (f32x4)0.f;

    const int l   = tid & 63;
    const int w   = tid >> 6;
    const int lr  = l & 15;
    const int lk8 = (l >> 4) * 8;

    int wp_[6], wco[6], wc4[6];
    #pragma unroll
    for (int i = 0; i < 6; ++i) {
        const int lin = i*256 + tid;
        wp_[i] = lin >> 9;
        const int r = lin & 511;
        wco[i] = r >> 3;
        wc4[i] = (r & 7) * 4;
    }

    float4 wreg[6];
    #pragma unroll
    for (int i = 0; i < 6; ++i)
        wreg[i] = *(const float4*)&Wp[wp_[i]][(size_t)(co0 + wco[i])*NC + wc4[i]];

    for (int kc = 0; kc < 8; ++kc) {
        __syncthreads();
        #pragma unroll
        for (int i = 0; i < 6; ++i) {
            bf16x4 wb;
            wb[0] = (__bf16)wreg[i].x; wb[1] = (__bf16)wreg[i].y;
            wb[2] = (__bf16)wreg[i].z; wb[3] = (__bf16)wreg[i].w;
            *(bf16x4*)&Ws[wp_[i]][wco[i]][wc4[i]] = wb;
        }
        __syncthreads();

        if (kc < 7) {
            #pragma unroll
            for (int i = 0; i < 6; ++i)
                wreg[i] = *(const float4*)&Wp[wp_[i]][(size_t)(co0 + wco[i])*NC + (kc+1)*32 + wc4[i]];
        }

        const bf16x8 a = *(const bf16x8*)&As[w*16 + lr][kc*32 + lk8];
        #pragma unroll
        for (int p = 0; p < 3; ++p)
            #pragma unroll
            for (int n = 0; n < 4; ++n) {
                const bf16x8 bfr = *(const bf16x8*)&Ws[p][n*16 + lr][lk8];
                acc[p][n] = mfma16x16x32(a, bfr, acc[p][n]);
            }
    }

    const int tba = t0 + w*16 + (l>>4)*4;   // base t of this thread's 4 rows

    // ---- Q, K: bias + relu (+QSCALE for Q), scalar bf16 store [b,h,t,j] ----
    {
        const float* bias2[2] = {bq, bk};
        __bf16* outp2[2] = {Qh, Kh};
        #pragma unroll
        for (int p = 0; p < 2; ++p) {
            #pragma unroll
            for (int n = 0; n < 4; ++n) {
                const int c  = co0 + n*16 + lr;
                const int hh = c >> 5, jj = c & 31;
                const float bv_ = bias2[p][c];
                const float sc  = (p == 0) ? QSCALE : 1.f;
                __bf16* op = outp2[p] + ((size_t)(bb*NH + hh)*NT)*ND + jj;
                #pragma unroll
                for (int r = 0; r < 4; ++r)
                    op[(size_t)(tba + r)*ND] = (__bf16)(fmaxf(acc[p][n][r] + bv_, 0.f) * sc);
            }
        }
    }

    // ---- V: bias + relu, key-mask zeroing, vectorized store [b,h,j,t] ----
    {
        float km[4];
        #pragma unroll
        for (int r = 0; r < 4; ++r)
            km[r] = (mask[bb*NT + tba + r] != 0) ? 1.f : 0.f;
        #pragma unroll
        for (int n = 0; n < 4; ++n) {
            const int c  = co0 + n*16 + lr;
            const int hh = c >> 5, jj = c & 31;
            const float bv_ = bv[c];
            bf16x4 vv;
            #pragma unroll
            for (int r = 0; r < 4; ++r)
                vv[r] = (__bf16)(fmaxf(acc[2][n][r] + bv_, 0.f) * km[r]);
            *(bf16x4*)&VhT[((size_t)(bb*NH + hh)*ND + jj)*NT + tba] = vv;
        }
    }
}

// =====================================================================
// Kernel 2: flash attention. 256 thr = 4 waves; wave w owns q-rows
// [w*32, w*32+32) (ct=0,1 sub-tiles of 16). s-chunks of 64.
//  - K staged in LDS [64][40] (r4 structure, measured best)
//  - V^T staged from pre-transposed global, b128 both sides, XOR-swizzled
//  - raw-max softmax: NO mask ops in inner loop (masked V rows are zero;
//    l = sum of masked P comes from an extra mask-column MFMA, accL)
//  - P -> bf16 PA (wave-private rows, swizzled); defer-max rescale
//  - setprio(1) around MFMA clusters (T5)
// Writes pre-BN x to out[b,c,t]; fused BN partial stats via atomics.
// =====================================================================
__global__ __launch_bounds__(256) void attn_mfma(
    const __bf16* __restrict__ Qh, const __bf16* __restrict__ Kh,
    const __bf16* __restrict__ VhT, const int* __restrict__ mask,
    float* __restrict__ xout, float* __restrict__ stats)
{
    __shared__ __bf16 Ks[64][40];     // [s][c]
    __shared__ __bf16 VTs[33*64];     // rows 0..31: V^T (swizzled); row 32: key-mask
    __shared__ __bf16 PA[128*64];     // [t][s] P bf16, swizzled, wave-private rows
    __shared__ float  bnsum[32][4];
    __shared__ float  bnsum2[32][4];

    const int tid = threadIdx.x;
    const int t0  = blockIdx.x * 128;
    const int h   = blockIdx.y;
    const int bb  = blockIdx.z;
    const int bh  = bb*NH + h;
    const __bf16* Qp = Qh  + (size_t)bh*NT*ND;
    const __bf16* Kp = Kh  + (size_t)bh*NT*ND;
    const __bf16* Vp = VhT + (size_t)bh*ND*NT;

    const int l   = tid & 63;
    const int w   = tid >> 6;       // wave 0..3
    const int lr  = l & 15;
    const int g   = l >> 4;         // 0..3
    const int swz = (lr & 7) << 3;  // XOR key, matches (row&7)<<3 on write side

    // Q B-fragments: constant all kernel.
    bf16x8 qb[2];
    #pragma unroll
    for (int ct = 0; ct < 2; ++ct)
        qb[ct] = *(const bf16x8*)&Qp[(size_t)(t0 + w*32 + ct*16 + lr)*ND + g*8];

    f32x4 accO[2][2];   // [jt][ct]: O^T[j=jt*16+g*4+r][t=w*32+ct*16+lr]
    f32x4 accL[2];      // [ct]: denominator l (all 4 regs equal)
    #pragma unroll
    for (int jt = 0; jt < 2; ++jt)
        #pragma unroll
        for (int ct = 0; ct < 2; ++ct) accO[jt][ct] = (f32x4)0.f;
    accL[0] = (f32x4)0.f; accL[1] = (f32x4)0.f;
    float m_run[2] = {-1e30f, -1e30f};

    // staging maps
    const int kv_s = tid >> 2, kv_c8 = (tid & 3) * 8;   // K: [s][c8] uint4
    const int vt_j = tid >> 3, vt_s8 = (tid & 7) * 8;   // V^T: [j][s8] uint4

    // preload chunk 0
    uint4 kreg = *(const uint4*)&Kp[(size_t)kv_s*ND + kv_c8];
    uint4 vreg = *(const uint4*)&Vp[(size_t)vt_j*NT + vt_s8];
    int   mreg = (tid < 64) ? mask[bb*NT + tid] : 0;

    for (int s0 = 0; s0 < NT; s0 += 64) {
        __syncthreads();   // prior chunk done reading Ks/VTs
        *(uint4*)&Ks[kv_s][kv_c8] = kreg;
        *(uint4*)&VTs[vt_j*64 + (vt_s8 ^ ((vt_j & 7) << 3))] = vreg;
        if (tid < 64) VTs[32*64 + tid] = (__bf16)(mreg ? 1.f : 0.f);
        __syncthreads();

        if (s0 + 64 < NT) {   // prefetch next chunk (hides under compute)
            const int sn = s0 + 64;
            kreg = *(const uint4*)&Kp[(size_t)(sn + kv_s)*ND + kv_c8];
            vreg = *(const uint4*)&Vp[(size_t)vt_j*NT + sn + vt_s8];
            if (tid < 64) mreg = mask[bb*NT + sn + tid];
        }

        // ---- QK^T (swapped): lane holds S^T[s=st*16+g*4+r][t=w*32+ct*16+lr]
        bf16x8 kA[4];
        #pragma unroll
        for (int st = 0; st < 4; ++st)
            kA[st] = *(const bf16x8*)&Ks[st*16 + lr][g*8];
        f32x4 sst[2][4];
        __builtin_amdgcn_s_setprio(1);
        #pragma unroll
        for (int ct = 0; ct < 2; ++ct)
            #pragma unroll
            for (int st = 0; st < 4; ++st)
                sst[ct][st] = mfma16x16x32(kA[st], qb[ct], (f32x4)0.f);
        __builtin_amdgcn_s_setprio(0);

        // ---- softmax: RAW max (no mask ops), exp2, P -> PA ----
        #pragma unroll
        for (int ct = 0; ct < 2; ++ct) {
            float mx = -1e30f;
            #pragma unroll
            for (int st = 0; st < 4; ++st)
                #pragma unroll
                for (int r = 0; r < 4; ++r) mx = fmaxf(mx, sst[ct][st][r]);
            mx = fmaxf(mx, __shfl_xor(mx, 16));
            mx = fmaxf(mx, __shfl_xor(mx, 32));

            if (!__all(mx <= m_run[ct] + DEFER_THR)) {
                const float m_new = fmaxf(m_run[ct], mx);
                const float f = exp2f(m_run[ct] - m_new);
                #pragma unroll
                for (int jt = 0; jt < 2; ++jt)
                    #pragma unroll
                    for (int r = 0; r < 4; ++r) accO[jt][ct][r] *= f;
                #pragma unroll
                for (int r = 0; r < 4; ++r) accL[ct][r] *= f;
                m_run[ct] = m_new;
            }

            const int trow = w*32 + ct*16 + lr;
            #pragma unroll
            for (int st = 0; st < 4; ++st) {
                bf16x4 pb4;
                #pragma unroll
                for (int r = 0; r < 4; ++r)
                    pb4[r] = (__bf16)exp2f(sst[ct][st][r] - m_run[ct]);
                *(bf16x4*)&PA[trow*64 + ((st*16 + g*4) ^ swz)] = pb4;
            }
        }

        // ---- PV + mask-column l: O^T += V^T @ P^T ; l += kb @ P^T ----
        __builtin_amdgcn_s_setprio(1);
        #pragma unroll
        for (int kh = 0; kh < 2; ++kh) {
            const int co = (kh*32 + g*8);
            bf16x8 va[2], pb[2];
            #pragma unroll
            for (int jt = 0; jt < 2; ++jt)
                va[jt] = *(const bf16x8*)&VTs[(jt*16 + lr)*64 + (co ^ swz)];
            const bf16x8 vam = *(const bf16x8*)&VTs[32*64 + co];   // broadcast row
            #pragma unroll
            for (int ct = 0; ct < 2; ++ct)
                pb[ct] = *(const bf16x8*)&PA[(w*32 + ct*16 + lr)*64 + (co ^ swz)];
            #pragma unroll
            for (int jt = 0; jt < 2; ++jt)
                #pragma unroll
                for (int ct = 0; ct < 2; ++ct)
                    accO[jt][ct] = mfma16x16x32(va[jt], pb[ct], accO[jt][ct]);
            #pragma unroll
            for (int ct = 0; ct < 2; ++ct)
                accL[ct] = mfma16x16x32(vam, pb[ct], accL[ct]);
        }
        __builtin_amdgcn_s_setprio(0);
    }

    // ---- epilogue: 1/l * qmask, store x[b,c,t]; fused BN partials ----
    float psum[2][4], psq[2][4];
    #pragma unroll
    for (int jt = 0; jt < 2; ++jt)
        #pragma unroll
        for (int r = 0; r < 4; ++r) { psum[jt][r] = 0.f; psq[jt][r] = 0.f; }

    #pragma unroll
    for (int ct = 0; ct < 2; ++ct) {
        const int t = t0 + w*32 + ct*16 + lr;
        const float rl = mask[bb*NT + t] ? (1.f / accL[ct][0]) : 0.f;
        #pragma unroll
        for (int jt = 0; jt < 2; ++jt) {
            #pragma unroll
            for (int r = 0; r < 4; ++r) {
                const int c = h*ND + jt*16 + g*4 + r;
                const float o = accO[jt][ct][r] * rl;
                xout[((size_t)(bb*NC + c))*NT + t] = o;
                psum[jt][r] += o;
                psq[jt][r]  += o*o;
            }
        }
    }
    #pragma unroll
    for (int jt = 0; jt < 2; ++jt)
        #pragma unroll
        for (int r = 0; r < 4; ++r)
            #pragma unroll
            for (int off = 1; off < 16; off <<= 1) {
                psum[jt][r] += __shfl_xor(psum[jt][r], off);
                psq[jt][r]  += __shfl_xor(psq[jt][r],  off);
            }
    if (lr == 0) {
        #pragma unroll
        for (int jt = 0; jt < 2; ++jt)
            #pragma unroll
            for (int r = 0; r < 4; ++r) {
                bnsum [jt*16 + g*4 + r][w] = psum[jt][r];
                bnsum2[jt*16 + g*4 + r][w] = psq[jt][r];
            }
    }
    __syncthreads();
    if (tid < 32) {
        const float s  = bnsum [tid][0] + bnsum [tid][1] + bnsum [tid][2] + bnsum [tid][3];
        const float s2 = bnsum2[tid][0] + bnsum2[tid][1] + bnsum2[tid][2] + bnsum2[tid][3];
        atomicAdd(&stats[h*ND + tid], s);
        atomicAdd(&stats[NC + h*ND + tid], s2);
    }
}

// =====================================================================
// Kernel 3: BN normalize + affine + re-mask, in place on d_out.
// =====================================================================
__global__ __launch_bounds__(256) void bn_apply_kernel(
    float* __restrict__ x, const float* __restrict__ stats,
    const float* __restrict__ gamma, const float* __restrict__ beta,
    const int* __restrict__ mask)
{
    const int idx = blockIdx.x*256 + threadIdx.x;
    const int t4 = idx & 127;
    const int c  = (idx >> 7) & 255;
    const int bb = idx >> 15;
    float4 v = ((const float4*)x)[idx];
    const int4 mk = *(const int4*)&mask[bb*NT + t4*4];
    const float mean = stats[c] * (1.f/16384.f);
    const float var  = fmaxf(stats[NC + c]*(1.f/16384.f) - mean*mean, 0.f);
    const float rstd = rsqrtf(var + 1e-5f);
    const float g = gamma[c], be = beta[c];
    v.x = mk.x ? fmaf((v.x - mean)*rstd, g, be) : 0.f;
    v.y = mk.y ? fmaf((v.y - mean)*rstd, g, be) : 0.f;
    v.z = mk.z ? fmaf((v.z - mean)*rstd, g, be) : 0.f;
    v.w = mk.w ? fmaf((v.w - mean)*rstd, g, be) : 0.f;
    ((float4*)x)[idx] = v;
}

extern "C" void kernel_launch(void* const* d_in, const int* in_sizes, int n_in,
                              void* d_out, int out_size, void* d_ws, size_t ws_size,
                              hipStream_t stream)
{
    const float* seq   = (const float*)d_in[0];
    const int*   mask  = (const int*)  d_in[1];
    const float* Wq    = (const float*)d_in[2];
    const float* bq    = (const float*)d_in[3];
    const float* Wk    = (const float*)d_in[4];
    const float* bk    = (const float*)d_in[5];
    const float* Wv    = (const float*)d_in[6];
    const float* bv    = (const float*)d_in[7];
    const float* gamma = (const float*)d_in[8];
    const float* beta  = (const float*)d_in[9];
    float* out = (float*)d_out;

    const size_t perMat = (size_t)NB*NH*NT*ND;
    __bf16* Qh  = (__bf16*)d_ws;
    __bf16* Kh  = Qh + perMat;
    __bf16* VhT = Kh + perMat;
    float* stats = (float*)(VhT + perMat);

    qkv_mfma<<<dim3(NT/64, NC/64, NB), 256, 0, stream>>>(
        seq, mask, Wq, bq, Wk, bk, Wv, bv, Qh, Kh, VhT, stats);
    attn_mfma<<<dim3(NT/128, NH, NB), 256, 0, stream>>>(
        Qh, Kh, VhT, mask, out, stats);
    bn_apply_kernel<<<dim3((NB*NC*NT/4)/256), 256, 0, stream>>>(
        out, stats, gamma, beta, mask);
}